// Round 3
// baseline (257.146 us; speedup 1.0000x reference)
//
#include <hip/hip_runtime.h>
#include <hip/hip_bf16.h>
#include <cstdint>

// Problem constants (match reference)
#define B_SZ     256
#define D_DIM    2048
#define N_PROXY  16384
#define P_POS    4
#define K_SEL    54        // BG_KNN + P
#define TEMP_INV 20.0f     // 1/0.05

typedef __bf16 bf16_t;
typedef __bf16 bf16x4 __attribute__((ext_vector_type(4)));
typedef __bf16 bf16x8 __attribute__((ext_vector_type(8)));
typedef float  f32x4  __attribute__((ext_vector_type(4)));

// ---------------------------------------------------------------------------
// Kernel 0: convert features fp32 -> bf16 once (1 MB, then L2/L3-resident).
// ---------------------------------------------------------------------------
__global__ __launch_bounds__(256)
void conv_feat(const float* __restrict__ F, bf16_t* __restrict__ Fb) {
    int i = blockIdx.x * 256 + threadIdx.x;          // 0..65535
    const float4* Fv = (const float4*)F;
    float4 a = Fv[2 * i], b = Fv[2 * i + 1];
    bf16x8 o = { (bf16_t)a.x, (bf16_t)a.y, (bf16_t)a.z, (bf16_t)a.w,
                 (bf16_t)b.x, (bf16_t)b.y, (bf16_t)b.z, (bf16_t)b.w };
    *(bf16x8*)(Fb + 8 * i) = o;
}

// ---------------------------------------------------------------------------
// Kernel 1: Sb = bf16((F @ em.T)/TEMP).  BM=256 (em read ONCE), BN=32, BK=64.
// Grid = 512 = 2 blocks/CU so barrier drains overlap across blocks.
// 256 threads = 4 waves (wave = 64-row m-block), wave-tile 64x32.
// A-fragments straight from global bf16 (L2-hot). B (em) fp32 streamed with
// 3-deep register prefetch into double-buffered LDS (24 KB/block in flight).
// ---------------------------------------------------------------------------
#define LDB 72   // bf16 per LDS row: 64 + 8 pad

__global__ __launch_bounds__(256, 2)
void gemm_score(const bf16_t* __restrict__ Fb, const float* __restrict__ E,
                bf16_t* __restrict__ Sb) {
    const int tid  = threadIdx.x;
    const int bn   = blockIdx.x;          // n-stripe: 32 em rows
    const int lane = tid & 63;
    const int wave = tid >> 6;            // m-block of 64 C rows
    const int frow = lane & 15;
    const int quad = lane >> 4;

    __shared__ bf16_t Bs[2][32 * LDB];    // 9.2 KB total

    f32x4 acc[4][2] = {};                 // [m][n], wave-tile 64x32

    const float* Ebase = E + (size_t)(bn * 32) * D_DIM;

    // staging map: B tile 32 rows x 64 k fp32 = 512 float4, 2 per thread
    int srow[2], scol[2];
    const float4* spv[2];
#pragma unroll
    for (int j = 0; j < 2; ++j) {
        int s = j * 256 + tid;
        srow[j] = s >> 4;                 // 16 float4 per row
        scol[j] = s & 15;
        spv[j]  = (const float4*)(Ebase + (size_t)srow[j] * D_DIM) + scol[j];
    }
    const bf16_t* arow[4];
#pragma unroll
    for (int m = 0; m < 4; ++m)
        arow[m] = Fb + (size_t)(wave * 64 + m * 16 + frow) * D_DIM + quad * 8;

    float4 rg[3][2];       // B prefetch, 3 steps deep
    bf16x8 ar[2][4][2];    // A frags double-banked: [bank][m][ksub]

    // ---- prologue: B loads for steps 0..2; A frags step 0; prime Bs[0] ----
#pragma unroll
    for (int p = 0; p < 3; ++p)
#pragma unroll
        for (int j = 0; j < 2; ++j) rg[p][j] = spv[j][p * 16];
#pragma unroll
    for (int m = 0; m < 4; ++m)
#pragma unroll
        for (int ks = 0; ks < 2; ++ks)
            ar[0][m][ks] = *(const bf16x8*)(arow[m] + ks * 32);
#pragma unroll
    for (int j = 0; j < 2; ++j) {
        float4 v = rg[0][j];
        bf16x4 h = { (bf16_t)v.x, (bf16_t)v.y, (bf16_t)v.z, (bf16_t)v.w };
        *(bf16x4*)&Bs[0][srow[j] * LDB + scol[j] * 4] = h;
    }
    __syncthreads();

#pragma unroll
    for (int kt = 0; kt < 32; ++kt) {
        const int cur = kt & 1, nxt = 1 - cur;
        // issue B loads 3 steps ahead
        if (kt + 3 < 32) {
#pragma unroll
            for (int j = 0; j < 2; ++j)
                rg[(kt + 3) % 3][j] = spv[j][(kt + 3) * 16];
        }
        // A frags 1 step ahead (L2-hot)
        if (kt + 1 < 32) {
#pragma unroll
            for (int m = 0; m < 4; ++m)
#pragma unroll
                for (int ks = 0; ks < 2; ++ks)
                    ar[nxt][m][ks] =
                        *(const bf16x8*)(arow[m] + (kt + 1) * 64 + ks * 32);
        }
        // compute on current LDS bank
#pragma unroll
        for (int ks = 0; ks < 2; ++ks) {
            bf16x8 bfrag[2];
#pragma unroll
            for (int n = 0; n < 2; ++n)
                bfrag[n] = *(const bf16x8*)&Bs[cur][(n * 16 + frow) * LDB +
                                                    ks * 32 + quad * 8];
#pragma unroll
            for (int m = 0; m < 4; ++m)
#pragma unroll
                for (int n = 0; n < 2; ++n)
                    acc[m][n] = __builtin_amdgcn_mfma_f32_16x16x32_bf16(
                        ar[cur][m][ks], bfrag[n], acc[m][n], 0, 0, 0);
        }
        // stage next step into the other bank
        if (kt + 1 < 32) {
#pragma unroll
            for (int j = 0; j < 2; ++j) {
                float4 v = rg[(kt + 1) % 3][j];
                bf16x4 h = { (bf16_t)v.x, (bf16_t)v.y,
                             (bf16_t)v.z, (bf16_t)v.w };
                *(bf16x4*)&Bs[nxt][srow[j] * LDB + scol[j] * 4] = h;
            }
        }
        __syncthreads();
    }

    // ---- epilogue: C/D layout col=lane&15, row=quad*4+i; fold 1/TEMP ----
#pragma unroll
    for (int m = 0; m < 4; ++m) {
        int gr = wave * 64 + m * 16 + quad * 4;
#pragma unroll
        for (int n = 0; n < 2; ++n) {
            int gc = bn * 32 + n * 16 + frow;
#pragma unroll
            for (int i = 0; i < 4; ++i)
                Sb[(size_t)(gr + i) * N_PROXY + gc] =
                    (bf16_t)(acc[m][n][i] * TEMP_INV);
        }
    }
}

// ---------------------------------------------------------------------------
// Kernel 2: per-row top-K + log-softmax loss on bf16 scores.
// 512 threads/row, 32 keys/thread in registers; 16-bit radix select with
// early exit; top-(P-d) via candidate compaction + single-wave max.
// ---------------------------------------------------------------------------
__device__ __forceinline__ float key16_to_float(uint32_t k) {
    uint32_t bits16 = (k & 0x8000u) ? (k ^ 0x8000u) : ((~k) & 0xFFFFu);
    return __uint_as_float(bits16 << 16);
}

__device__ __forceinline__ int block_sum_i(int v, int tid, volatile int* rbuf) {
#pragma unroll
    for (int o = 32; o > 0; o >>= 1) v += __shfl_down(v, o, 64);
    __syncthreads();
    if ((tid & 63) == 0) rbuf[tid >> 6] = v;
    __syncthreads();
    int s = 0;
#pragma unroll
    for (int w = 0; w < 8; ++w) s += rbuf[w];
    return s;
}

__device__ __forceinline__ float block_sum_f(float v, int tid, volatile float* rbuf) {
#pragma unroll
    for (int o = 32; o > 0; o >>= 1) v += __shfl_down(v, o, 64);
    __syncthreads();
    if ((tid & 63) == 0) rbuf[tid >> 6] = v;
    __syncthreads();
    float s = 0.0f;
#pragma unroll
    for (int w = 0; w < 8; ++w) s += rbuf[w];
    return s;
}

__device__ __forceinline__ uint32_t block_max_u(uint32_t v, int tid,
                                                volatile uint32_t* rbuf) {
#pragma unroll
    for (int o = 32; o > 0; o >>= 1) {
        uint32_t w = __shfl_down(v, o, 64);
        v = (w > v) ? w : v;
    }
    __syncthreads();
    if ((tid & 63) == 0) rbuf[tid >> 6] = v;
    __syncthreads();
    uint32_t r = 0;
#pragma unroll
    for (int w = 0; w < 8; ++w) r = rbuf[w] > r ? rbuf[w] : r;
    return r;
}

__global__ __launch_bounds__(512)
void topk_loss(const bf16_t* __restrict__ S, const int* __restrict__ targets,
               const int* __restrict__ plabel, const int* __restrict__ ptable,
               float* __restrict__ out) {
    const int b    = blockIdx.x;
    const int tid  = threadIdx.x;
    const int lane = tid & 63;
    const int wave = tid >> 6;

    __shared__ int      sh_pos[4];
    __shared__ float    sh_pv[4];
    __shared__ int      sh_d;
    __shared__ int      rbuf_i[8];
    __shared__ float    rbuf_f[8];
    __shared__ uint32_t rbuf_u[8];
    __shared__ uint32_t cand_ls[64];
    __shared__ int      candcnt;
    __shared__ float    sh_numbg;

    const bf16_t* row = S + (size_t)b * N_PROXY;

    if (tid == 0) {
        int t  = targets[b];
        int py = plabel[t];
        int pos[4]; int d = 0;
        for (int j = 0; j < 4; ++j) {
            int p = ptable[py * 4 + j];
            bool dup = false;
            for (int i = 0; i < d; ++i) dup = dup || (pos[i] == p);
            if (!dup) pos[d++] = p;
        }
        sh_d = d;
        for (int j = 0; j < 4; ++j) sh_pos[j] = (j < d) ? pos[j] : -1;
        for (int j = 0; j < 4; ++j) sh_pv[j]  = (j < d) ? (float)row[pos[j]] : 0.0f;
        candcnt = 0;
    }
    __syncthreads();

    const int d  = sh_d;
    const int p0 = sh_pos[0], p1 = sh_pos[1], p2 = sh_pos[2], p3 = sh_pos[3];
    float pv[4];
#pragma unroll
    for (int j = 0; j < 4; ++j) pv[j] = sh_pv[j];

    // ---- 32 bf16 logits/thread as 16-bit sortable keys; positives -> 0 ----
    uint32_t keys[32];
#pragma unroll
    for (int j = 0; j < 4; ++j) {
        int g8 = j * 512 + tid;                     // 8-element granule
        ushort v[8];
        *(uint4*)v = *(const uint4*)(row + (size_t)g8 * 8);
#pragma unroll
        for (int q = 0; q < 8; ++q) {
            int idx = g8 * 8 + q;
            bool isp = (idx == p0) | (idx == p1) | (idx == p2) | (idx == p3);
            uint32_t bits = v[q];
            uint32_t key  = (bits & 0x8000u) ? ((~bits) & 0xFFFFu)
                                             : (bits | 0x8000u);
            keys[j * 8 + q] = isp ? 0u : key;
        }
    }

    const int need = K_SEL - d;              // backgrounds in the top-54 set

    // ---- 16-bit radix select with early exit ----
    uint32_t T = 0;
    for (int bit = 15; bit >= 0; --bit) {
        uint32_t cnd = T | (1u << bit);
        int c = 0;
#pragma unroll
        for (int j = 0; j < 32; ++j) c += (keys[j] >= cnd) ? 1 : 0;
        int ct = block_sum_i(c, tid, rbuf_i);
        if (ct >= need) {
            T = cnd;
            if (ct == need) break;           // selected set is exactly top-need
        }
    }
    const float vT = key16_to_float(T);

    // ---- stability max over backgrounds + positives ----
    uint32_t kmax = 0;
#pragma unroll
    for (int j = 0; j < 32; ++j) kmax = keys[j] > kmax ? keys[j] : kmax;
    kmax = block_max_u(kmax, tid, rbuf_u);
    float mx = key16_to_float(kmax);
    for (int j = 0; j < 4; ++j) if (j < d && pv[j] > mx) mx = pv[j];

    // ---- lse over selected set: strict-greater + exact tie fill + pos ----
    int c1 = 0; float se = 0.0f;
#pragma unroll
    for (int j = 0; j < 32; ++j) {
        if (keys[j] > T) { c1 += 1; se += __expf(key16_to_float(keys[j]) - mx); }
    }
    int   c1t = block_sum_i(c1, tid, rbuf_i);
    float set = block_sum_f(se, tid, rbuf_f);
    set += (float)(need - c1t) * __expf(vT - mx);
    for (int j = 0; j < 4; ++j) if (j < d) set += __expf(pv[j] - mx);
    const float lse = mx + logf(set);

    // ---- numerator: distinct positives + top (P-d) background values ----
    float num = 0.0f;
    for (int j = 0; j < 4; ++j) if (j < d) num += pv[j];
    if (d < P_POS) {
#pragma unroll
        for (int j = 0; j < 32; ++j) {
            if (keys[j] > T) {
                int p = atomicAdd(&candcnt, 1);
                cand_ls[p] = keys[j];
            }
        }
        __syncthreads();
        if (wave == 0) {
            const int cc = candcnt;
            uint32_t v = (lane < cc) ? cand_ls[lane] : T;   // pad with T (exact)
            float s = 0.0f;
            const int need2 = P_POS - d;                    // 1..3
            for (int it = 0; it < need2; ++it) {
                uint32_t m = v;
#pragma unroll
                for (int o = 32; o > 0; o >>= 1) {
                    uint32_t w = __shfl_xor(m, o, 64);
                    m = (w > m) ? w : m;
                }
                s += key16_to_float(m);
                unsigned long long msk = __ballot(v == m);
                int first = __ffsll(msk) - 1;
                if (lane == first) v = 0u;
            }
            if (lane == 0) sh_numbg = s;
        }
        __syncthreads();
        num += sh_numbg;
    }

    const float loss_b = lse - num * (1.0f / P_POS);
    if (tid == 0) atomicAdd(out, loss_b * (1.0f / B_SZ));
}

// ---------------------------------------------------------------------------
extern "C" void kernel_launch(void* const* d_in, const int* in_sizes, int n_in,
                              void* d_out, int out_size, void* d_ws, size_t ws_size,
                              hipStream_t stream) {
    const float* F       = (const float*)d_in[0];   // features [256,2048]
    const float* E       = (const float*)d_in[1];   // global_memory [16384,2048]
    const int*   targets = (const int*)d_in[2];     // [256]
    const int*   plabel  = (const int*)d_in[3];     // [32768]
    const int*   ptable  = (const int*)d_in[4];     // [4096,4]

    bf16_t* Fb = (bf16_t*)d_ws;                                     // 1 MB
    bf16_t* Sb = (bf16_t*)((char*)d_ws + (size_t)B_SZ * D_DIM * 2); // 8 MB
    float*  out = (float*)d_out;

    hipMemsetAsync(d_out, 0, sizeof(float), stream);

    hipLaunchKernelGGL(conv_feat, dim3(256), dim3(256), 0, stream, F, Fb);
    hipLaunchKernelGGL(gemm_score, dim3(N_PROXY / 32), dim3(256), 0, stream,
                       Fb, E, Sb);
    hipLaunchKernelGGL(topk_loss, dim3(B_SZ), dim3(512), 0, stream,
                       Sb, targets, plabel, ptable, out);
}

// Round 4
// 257.048 us; speedup vs baseline: 1.0004x; 1.0004x over previous
//
#include <hip/hip_runtime.h>
#include <hip/hip_bf16.h>
#include <cstdint>

// Problem constants (match reference)
#define B_SZ     256
#define D_DIM    2048
#define N_PROXY  16384
#define P_POS    4
#define K_SEL    54        // BG_KNN + P
#define TEMP_INV 20.0f     // 1/0.05

typedef __bf16 bf16_t;
typedef __bf16 bf16x4 __attribute__((ext_vector_type(4)));
typedef __bf16 bf16x8 __attribute__((ext_vector_type(8)));
typedef float  f32x4  __attribute__((ext_vector_type(4)));

// ---------------------------------------------------------------------------
// Kernel 0: F fp32 [256,2048] -> Fb bf16 in MFMA-A fragment-major layout.
// frag slot g = (mb*64 + kt)*64 + lane holds A[m=mb*16+(lane&15)]
// [k = kt*32 + (lane>>4)*8 + j], j=0..7.  GEMM A-load becomes one coalesced
// 1 KB dwordx4 per wave. 65536 threads, 16 B out each.
// ---------------------------------------------------------------------------
__global__ __launch_bounds__(256)
void conv_feat(const float* __restrict__ F, bf16_t* __restrict__ Fb) {
    int g    = blockIdx.x * 256 + threadIdx.x;   // 0..65535
    int lane = g & 63;
    int kt   = (g >> 6) & 63;
    int mb   = g >> 12;                          // 0..15
    int frow = lane & 15;
    int quad = (lane >> 4) & 3;
    const float* src = F + (size_t)(mb * 16 + frow) * D_DIM + kt * 32 + quad * 8;
    float4 lo = *(const float4*)src;
    float4 hi = *(const float4*)(src + 4);
    bf16x8 o = { (bf16_t)lo.x, (bf16_t)lo.y, (bf16_t)lo.z, (bf16_t)lo.w,
                 (bf16_t)hi.x, (bf16_t)hi.y, (bf16_t)hi.z, (bf16_t)hi.w };
    *(bf16x8*)(Fb + (size_t)g * 8) = o;
}

// ---------------------------------------------------------------------------
// Kernel 1: Sb = bf16((F @ em.T)/TEMP).  NO LDS, NO BARRIERS in the K-loop.
// Grid 256 x 256 thr: block = 64-col stripe, 4 waves split M (wave 64x64).
// A from fragment-major Fb (coalesced, L2-hot). B fp32 direct per-wave
// fragment loads (16-line divergent but lines fully used; 4-wave duplicate
// reads dedup in L2), converted to bf16 in-register. 2-step reg prefetch.
// ---------------------------------------------------------------------------
__global__ __launch_bounds__(256, 1)
void gemm_score(const bf16_t* __restrict__ Fb, const float* __restrict__ E,
                bf16_t* __restrict__ Sb) {
    const int tid  = threadIdx.x;
    const int bn   = blockIdx.x;          // 64-col n-stripe
    const int lane = tid & 63;
    const int wave = tid >> 6;            // 64-row m-block
    const int frow = lane & 15;
    const int quad = (lane >> 4) & 3;

    f32x4 acc[4][4] = {};                 // [m][n]

    // A frag (m, kt) at Fb[((wave*4+m)*64 + kt)*512 + lane*8]
    const bf16_t* Ab[4];
#pragma unroll
    for (int m = 0; m < 4; ++m)
        Ab[m] = Fb + ((size_t)((wave * 4 + m) * 64) * 512) + lane * 8;

    // B frag (n, kt): em[row = bn*64+n*16+frow][k = kt*32 + quad*8 .. +8]
    const float* Bb[4];
#pragma unroll
    for (int n = 0; n < 4; ++n)
        Bb[n] = E + (size_t)(bn * 64 + n * 16 + frow) * D_DIM + quad * 8;

    bf16x8 Ar[2][4];        // A prefetch banks
    float4 Br[2][4][2];     // B prefetch banks (fp32)

    // ---- prologue: load kt=0 and kt=1 ----
#pragma unroll
    for (int c = 0; c < 2; ++c) {
#pragma unroll
        for (int m = 0; m < 4; ++m)
            Ar[c][m] = *(const bf16x8*)(Ab[m] + c * 512);
#pragma unroll
        for (int n = 0; n < 4; ++n) {
            Br[c][n][0] = *(const float4*)(Bb[n] + c * 32);
            Br[c][n][1] = *(const float4*)(Bb[n] + c * 32 + 4);
        }
    }

#define STEP(KT, C)                                                            \
    {                                                                          \
        bf16x8 af[4], bg[4];                                                   \
        _Pragma("unroll")                                                      \
        for (int m = 0; m < 4; ++m) af[m] = Ar[C][m];                          \
        _Pragma("unroll")                                                      \
        for (int n = 0; n < 4; ++n) {                                          \
            float4 lo = Br[C][n][0], hi = Br[C][n][1];                         \
            bg[n] = (bf16x8){ (bf16_t)lo.x, (bf16_t)lo.y, (bf16_t)lo.z,        \
                              (bf16_t)lo.w, (bf16_t)hi.x, (bf16_t)hi.y,        \
                              (bf16_t)hi.z, (bf16_t)hi.w };                    \
        }                                                                      \
        if ((KT) + 2 < 64) {                                                   \
            _Pragma("unroll")                                                  \
            for (int m = 0; m < 4; ++m)                                        \
                Ar[C][m] = *(const bf16x8*)(Ab[m] + ((KT) + 2) * 512);         \
            _Pragma("unroll")                                                  \
            for (int n = 0; n < 4; ++n) {                                      \
                Br[C][n][0] = *(const float4*)(Bb[n] + ((KT) + 2) * 32);       \
                Br[C][n][1] = *(const float4*)(Bb[n] + ((KT) + 2) * 32 + 4);   \
            }                                                                  \
        }                                                                      \
        _Pragma("unroll")                                                      \
        for (int m = 0; m < 4; ++m)                                            \
            _Pragma("unroll")                                                  \
            for (int n = 0; n < 4; ++n)                                        \
                acc[m][n] = __builtin_amdgcn_mfma_f32_16x16x32_bf16(           \
                    af[m], bg[n], acc[m][n], 0, 0, 0);                         \
    }

    for (int kt = 0; kt < 64; kt += 2) {
        STEP(kt, 0)
        STEP(kt + 1, 1)
    }
#undef STEP

    // ---- epilogue: C/D layout col=lane&15, row=quad*4+i; fold 1/TEMP ----
#pragma unroll
    for (int m = 0; m < 4; ++m) {
        int gr = wave * 64 + m * 16 + quad * 4;
#pragma unroll
        for (int n = 0; n < 4; ++n) {
            int gc = bn * 64 + n * 16 + frow;
#pragma unroll
            for (int i = 0; i < 4; ++i)
                Sb[(size_t)(gr + i) * N_PROXY + gc] =
                    (bf16_t)(acc[m][n][i] * TEMP_INV);
        }
    }
}

// ---------------------------------------------------------------------------
// Kernel 2: per-row top-K + log-softmax loss on bf16 scores.
// 512 threads/row, 32 keys/thread; 16-bit radix select with early exit.
// ---------------------------------------------------------------------------
__device__ __forceinline__ float key16_to_float(uint32_t k) {
    uint32_t bits16 = (k & 0x8000u) ? (k ^ 0x8000u) : ((~k) & 0xFFFFu);
    return __uint_as_float(bits16 << 16);
}

__device__ __forceinline__ int block_sum_i(int v, int tid, volatile int* rbuf) {
#pragma unroll
    for (int o = 32; o > 0; o >>= 1) v += __shfl_down(v, o, 64);
    __syncthreads();
    if ((tid & 63) == 0) rbuf[tid >> 6] = v;
    __syncthreads();
    int s = 0;
#pragma unroll
    for (int w = 0; w < 8; ++w) s += rbuf[w];
    return s;
}

__device__ __forceinline__ float block_sum_f(float v, int tid, volatile float* rbuf) {
#pragma unroll
    for (int o = 32; o > 0; o >>= 1) v += __shfl_down(v, o, 64);
    __syncthreads();
    if ((tid & 63) == 0) rbuf[tid >> 6] = v;
    __syncthreads();
    float s = 0.0f;
#pragma unroll
    for (int w = 0; w < 8; ++w) s += rbuf[w];
    return s;
}

__device__ __forceinline__ uint32_t block_max_u(uint32_t v, int tid,
                                                volatile uint32_t* rbuf) {
#pragma unroll
    for (int o = 32; o > 0; o >>= 1) {
        uint32_t w = __shfl_down(v, o, 64);
        v = (w > v) ? w : v;
    }
    __syncthreads();
    if ((tid & 63) == 0) rbuf[tid >> 6] = v;
    __syncthreads();
    uint32_t r = 0;
#pragma unroll
    for (int w = 0; w < 8; ++w) r = rbuf[w] > r ? rbuf[w] : r;
    return r;
}

__global__ __launch_bounds__(512)
void topk_loss(const bf16_t* __restrict__ S, const int* __restrict__ targets,
               const int* __restrict__ plabel, const int* __restrict__ ptable,
               float* __restrict__ out) {
    const int b    = blockIdx.x;
    const int tid  = threadIdx.x;
    const int lane = tid & 63;
    const int wave = tid >> 6;

    __shared__ int      sh_pos[4];
    __shared__ float    sh_pv[4];
    __shared__ int      sh_d;
    __shared__ int      rbuf_i[8];
    __shared__ float    rbuf_f[8];
    __shared__ uint32_t rbuf_u[8];
    __shared__ uint32_t cand_ls[64];
    __shared__ int      candcnt;
    __shared__ float    sh_numbg;

    const bf16_t* row = S + (size_t)b * N_PROXY;

    if (tid == 0) {
        int t  = targets[b];
        int py = plabel[t];
        int pos[4]; int d = 0;
        for (int j = 0; j < 4; ++j) {
            int p = ptable[py * 4 + j];
            bool dup = false;
            for (int i = 0; i < d; ++i) dup = dup || (pos[i] == p);
            if (!dup) pos[d++] = p;
        }
        sh_d = d;
        for (int j = 0; j < 4; ++j) sh_pos[j] = (j < d) ? pos[j] : -1;
        for (int j = 0; j < 4; ++j) sh_pv[j]  = (j < d) ? (float)row[pos[j]] : 0.0f;
        candcnt = 0;
    }
    __syncthreads();

    const int d  = sh_d;
    const int p0 = sh_pos[0], p1 = sh_pos[1], p2 = sh_pos[2], p3 = sh_pos[3];
    float pv[4];
#pragma unroll
    for (int j = 0; j < 4; ++j) pv[j] = sh_pv[j];

    // ---- 32 bf16 logits/thread as 16-bit sortable keys; positives -> 0 ----
    uint32_t keys[32];
#pragma unroll
    for (int j = 0; j < 4; ++j) {
        int g8 = j * 512 + tid;                     // 8-element granule
        ushort v[8];
        *(uint4*)v = *(const uint4*)(row + (size_t)g8 * 8);
#pragma unroll
        for (int q = 0; q < 8; ++q) {
            int idx = g8 * 8 + q;
            bool isp = (idx == p0) | (idx == p1) | (idx == p2) | (idx == p3);
            uint32_t bits = v[q];
            uint32_t key  = (bits & 0x8000u) ? ((~bits) & 0xFFFFu)
                                             : (bits | 0x8000u);
            keys[j * 8 + q] = isp ? 0u : key;
        }
    }

    const int need = K_SEL - d;              // backgrounds in the top-54 set

    // ---- 16-bit radix select with early exit ----
    uint32_t T = 0;
    for (int bit = 15; bit >= 0; --bit) {
        uint32_t cnd = T | (1u << bit);
        int c = 0;
#pragma unroll
        for (int j = 0; j < 32; ++j) c += (keys[j] >= cnd) ? 1 : 0;
        int ct = block_sum_i(c, tid, rbuf_i);
        if (ct >= need) {
            T = cnd;
            if (ct == need) break;           // selected set is exactly top-need
        }
    }
    const float vT = key16_to_float(T);

    // ---- stability max over backgrounds + positives ----
    uint32_t kmax = 0;
#pragma unroll
    for (int j = 0; j < 32; ++j) kmax = keys[j] > kmax ? keys[j] : kmax;
    kmax = block_max_u(kmax, tid, rbuf_u);
    float mx = key16_to_float(kmax);
    for (int j = 0; j < 4; ++j) if (j < d && pv[j] > mx) mx = pv[j];

    // ---- lse over selected set: strict-greater + exact tie fill + pos ----
    int c1 = 0; float se = 0.0f;
#pragma unroll
    for (int j = 0; j < 32; ++j) {
        if (keys[j] > T) { c1 += 1; se += __expf(key16_to_float(keys[j]) - mx); }
    }
    int   c1t = block_sum_i(c1, tid, rbuf_i);
    float set = block_sum_f(se, tid, rbuf_f);
    set += (float)(need - c1t) * __expf(vT - mx);
    for (int j = 0; j < 4; ++j) if (j < d) set += __expf(pv[j] - mx);
    const float lse = mx + logf(set);

    // ---- numerator: distinct positives + top (P-d) background values ----
    float num = 0.0f;
    for (int j = 0; j < 4; ++j) if (j < d) num += pv[j];
    if (d < P_POS) {
#pragma unroll
        for (int j = 0; j < 32; ++j) {
            if (keys[j] > T) {
                int p = atomicAdd(&candcnt, 1);
                cand_ls[p] = keys[j];
            }
        }
        __syncthreads();
        if (wave == 0) {
            const int cc = candcnt;
            uint32_t v = (lane < cc) ? cand_ls[lane] : T;   // pad with T (exact)
            float s = 0.0f;
            const int need2 = P_POS - d;                    // 1..3
            for (int it = 0; it < need2; ++it) {
                uint32_t m = v;
#pragma unroll
                for (int o = 32; o > 0; o >>= 1) {
                    uint32_t w = __shfl_xor(m, o, 64);
                    m = (w > m) ? w : m;
                }
                s += key16_to_float(m);
                unsigned long long msk = __ballot(v == m);
                int first = __ffsll(msk) - 1;
                if (lane == first) v = 0u;
            }
            if (lane == 0) sh_numbg = s;
        }
        __syncthreads();
        num += sh_numbg;
    }

    const float loss_b = lse - num * (1.0f / P_POS);
    if (tid == 0) atomicAdd(out, loss_b * (1.0f / B_SZ));
}

// ---------------------------------------------------------------------------
extern "C" void kernel_launch(void* const* d_in, const int* in_sizes, int n_in,
                              void* d_out, int out_size, void* d_ws, size_t ws_size,
                              hipStream_t stream) {
    const float* F       = (const float*)d_in[0];   // features [256,2048]
    const float* E       = (const float*)d_in[1];   // global_memory [16384,2048]
    const int*   targets = (const int*)d_in[2];     // [256]
    const int*   plabel  = (const int*)d_in[3];     // [32768]
    const int*   ptable  = (const int*)d_in[4];     // [4096,4]

    bf16_t* Fb = (bf16_t*)d_ws;                                     // 1 MB, frag-major
    bf16_t* Sb = (bf16_t*)((char*)d_ws + (size_t)B_SZ * D_DIM * 2); // 8 MB
    float*  out = (float*)d_out;

    hipMemsetAsync(d_out, 0, sizeof(float), stream);

    hipLaunchKernelGGL(conv_feat, dim3(256), dim3(256), 0, stream, F, Fb);
    hipLaunchKernelGGL(gemm_score, dim3(N_PROXY / 64), dim3(256), 0, stream,
                       Fb, E, Sb);
    hipLaunchKernelGGL(topk_loss, dim3(B_SZ), dim3(512), 0, stream,
                       Sb, targets, plabel, ptable, out);
}

// Round 5
// 246.362 us; speedup vs baseline: 1.0438x; 1.0434x over previous
//
#include <hip/hip_runtime.h>
#include <hip/hip_bf16.h>
#include <cstdint>

// Problem constants (match reference)
#define B_SZ     256
#define D_DIM    2048
#define N_PROXY  16384
#define P_POS    4
#define K_SEL    54        // BG_KNN + P
#define TEMP_INV 20.0f     // 1/0.05

typedef __bf16 bf16_t;
typedef __bf16 bf16x4 __attribute__((ext_vector_type(4)));
typedef __bf16 bf16x8 __attribute__((ext_vector_type(8)));
typedef float  f32x4  __attribute__((ext_vector_type(4)));

// ---------------------------------------------------------------------------
// Kernel 0: F fp32 [256,2048] -> Fb bf16 in MFMA-A fragment-major layout.
// frag slot g = (mb*64 + kt)*64 + lane holds A[m=mb*16+(lane&15)]
// [k = kt*32 + (lane>>4)*8 + j], j=0..7.  GEMM A-load = one coalesced 1 KB
// dwordx4 per wave (8 full lines). 65536 threads, 16 B out each.
// ---------------------------------------------------------------------------
__global__ __launch_bounds__(256)
void conv_feat(const float* __restrict__ F, bf16_t* __restrict__ Fb) {
    int g    = blockIdx.x * 256 + threadIdx.x;   // 0..65535
    int lane = g & 63;
    int kt   = (g >> 6) & 63;
    int mb   = g >> 12;                          // 0..15
    int frow = lane & 15;
    int quad = (lane >> 4) & 3;
    const float* src = F + (size_t)(mb * 16 + frow) * D_DIM + kt * 32 + quad * 8;
    float4 lo = *(const float4*)src;
    float4 hi = *(const float4*)(src + 4);
    bf16x8 o = { (bf16_t)lo.x, (bf16_t)lo.y, (bf16_t)lo.z, (bf16_t)lo.w,
                 (bf16_t)hi.x, (bf16_t)hi.y, (bf16_t)hi.z, (bf16_t)hi.w };
    *(bf16x8*)(Fb + (size_t)g * 8) = o;
}

// ---------------------------------------------------------------------------
// Kernel 1: Sb = bf16((F @ em.T)/TEMP).  BM=256, BN=64, BK=32, grid 256.
// EVERY global load is <=8-line coalesced (the r3/r4 killer was 16-line
// divergent gathers at ~5.5 cyc/line/CU). A: frag-major Fb, direct to regs.
// B: row-coalesced float4 -> 4-deep reg prefetch -> cvt -> WAVE-PRIVATE
// frag-major LDS (no __syncthreads in the K-loop => no vmcnt(0) drains).
// ---------------------------------------------------------------------------
__global__ __launch_bounds__(256, 1)
void gemm_score(const bf16_t* __restrict__ Fb, const float* __restrict__ E,
                bf16_t* __restrict__ Sb) {
    const int tid  = threadIdx.x;
    const int bn   = blockIdx.x;          // 64-col n-stripe
    const int lane = tid & 63;
    const int wave = tid >> 6;            // 64-row m-block
    const int frow = lane & 15;
    const int quad = (lane >> 4) & 3;

    // wave-private double-buffered B in MFMA-B fragment-major layout:
    // frag n (512 bf16 = 1 KB) at n*512, lane-slot l' = frow+16*quad at l'*8.
    __shared__ bf16_t Bls[4][2][2048];    // [wave][buf][4 frags] = 32 KB

    f32x4 acc[4][4] = {};                 // [m][n]

    // ---- B staging addresses: slab = 64 rows x 32 fp32 (128 B/row-seg).
    // instr j stages rows j*8..j*8+7; lanes 0-7 cover one 128-B row segment.
    const int brow = lane >> 3;           // row-within-8
    const int c4   = (lane & 7) * 4;      // float col within 32
    const float* bsrc[8];
#pragma unroll
    for (int j = 0; j < 8; ++j)
        bsrc[j] = E + (size_t)(bn * 64 + j * 8 + brow) * D_DIM + c4;
    // LDS dest (bf16 units) for instr j's converted bf16x4:
    int bdst[8];
#pragma unroll
    for (int j = 0; j < 8; ++j) {
        int r    = j * 8 + brow;
        int n    = r >> 4;
        int fr   = r & 15;
        int qd   = c4 >> 3;
        int half = (c4 >> 2) & 1;
        bdst[j] = n * 512 + (fr + 16 * qd) * 8 + half * 4;
    }

    // A frag (m, kt) at Fb[((wave*4+m)*64 + kt)*512 + lane*8]
    const bf16_t* Ab[4];
#pragma unroll
    for (int m = 0; m < 4; ++m)
        Ab[m] = Fb + ((size_t)((wave * 4 + m) * 64) * 512) + lane * 8;

    float4 Brg[4][8];      // B prefetch, 4 steps deep (3 in flight)
    bf16x8 af[2][4];       // A frags, 1 step ahead

    bf16_t* lds = &Bls[wave][0][0];

    // ---- prologue: B(0..3) loads, A(0) loads, stage B(0) into buf 0 ----
#pragma unroll
    for (int p = 0; p < 4; ++p)
#pragma unroll
        for (int j = 0; j < 8; ++j)
            Brg[p][j] = *(const float4*)(bsrc[j] + p * 32);
#pragma unroll
    for (int m = 0; m < 4; ++m)
        af[0][m] = *(const bf16x8*)(Ab[m]);
#pragma unroll
    for (int j = 0; j < 8; ++j) {
        float4 v = Brg[0][j];
        bf16x4 h = { (bf16_t)v.x, (bf16_t)v.y, (bf16_t)v.z, (bf16_t)v.w };
        *(bf16x4*)(lds + bdst[j]) = h;
    }

#define STEP(KT)                                                               \
    {                                                                          \
        const int cur_ = (KT) & 1, nxt_ = 1 - cur_;                            \
        if ((KT) + 4 < 64) {                                                   \
            _Pragma("unroll")                                                  \
            for (int j = 0; j < 8; ++j)                                        \
                Brg[(KT) & 3][j] = *(const float4*)(bsrc[j] + ((KT) + 4) * 32);\
        }                                                                      \
        if ((KT) + 1 < 64) {                                                   \
            _Pragma("unroll")                                                  \
            for (int m = 0; m < 4; ++m)                                        \
                af[nxt_][m] = *(const bf16x8*)(Ab[m] + ((KT) + 1) * 512);      \
        }                                                                      \
        bf16x8 bg[4];                                                          \
        _Pragma("unroll")                                                      \
        for (int n = 0; n < 4; ++n)                                            \
            bg[n] = *(const bf16x8*)(lds + cur_ * 2048 + n * 512 + lane * 8);  \
        _Pragma("unroll")                                                      \
        for (int m = 0; m < 4; ++m)                                            \
            _Pragma("unroll")                                                  \
            for (int n = 0; n < 4; ++n)                                        \
                acc[m][n] = __builtin_amdgcn_mfma_f32_16x16x32_bf16(           \
                    af[cur_][m], bg[n], acc[m][n], 0, 0, 0);                   \
        if ((KT) + 1 < 64) {                                                   \
            _Pragma("unroll")                                                  \
            for (int j = 0; j < 8; ++j) {                                      \
                float4 v = Brg[((KT) + 1) & 3][j];                             \
                bf16x4 h = { (bf16_t)v.x, (bf16_t)v.y,                         \
                             (bf16_t)v.z, (bf16_t)v.w };                       \
                *(bf16x4*)(lds + nxt_ * 2048 + bdst[j]) = h;                   \
            }                                                                  \
        }                                                                      \
    }

    for (int k0 = 0; k0 < 64; k0 += 4) {
        STEP(k0 + 0)
        STEP(k0 + 1)
        STEP(k0 + 2)
        STEP(k0 + 3)
    }
#undef STEP

    // ---- epilogue: C/D layout col=lane&15, row=quad*4+i; fold 1/TEMP ----
#pragma unroll
    for (int m = 0; m < 4; ++m) {
        int gr = wave * 64 + m * 16 + quad * 4;
#pragma unroll
        for (int n = 0; n < 4; ++n) {
            int gc = bn * 64 + n * 16 + frow;
#pragma unroll
            for (int i = 0; i < 4; ++i)
                Sb[(size_t)(gr + i) * N_PROXY + gc] =
                    (bf16_t)(acc[m][n][i] * TEMP_INV);
        }
    }
}

// ---------------------------------------------------------------------------
// Kernel 2: per-row top-K + log-softmax loss on bf16 scores.
// 512 threads/row, 32 keys/thread; 16-bit radix select with early exit.
// ---------------------------------------------------------------------------
__device__ __forceinline__ float key16_to_float(uint32_t k) {
    uint32_t bits16 = (k & 0x8000u) ? (k ^ 0x8000u) : ((~k) & 0xFFFFu);
    return __uint_as_float(bits16 << 16);
}

__device__ __forceinline__ int block_sum_i(int v, int tid, volatile int* rbuf) {
#pragma unroll
    for (int o = 32; o > 0; o >>= 1) v += __shfl_down(v, o, 64);
    __syncthreads();
    if ((tid & 63) == 0) rbuf[tid >> 6] = v;
    __syncthreads();
    int s = 0;
#pragma unroll
    for (int w = 0; w < 8; ++w) s += rbuf[w];
    return s;
}

__device__ __forceinline__ float block_sum_f(float v, int tid, volatile float* rbuf) {
#pragma unroll
    for (int o = 32; o > 0; o >>= 1) v += __shfl_down(v, o, 64);
    __syncthreads();
    if ((tid & 63) == 0) rbuf[tid >> 6] = v;
    __syncthreads();
    float s = 0.0f;
#pragma unroll
    for (int w = 0; w < 8; ++w) s += rbuf[w];
    return s;
}

__device__ __forceinline__ uint32_t block_max_u(uint32_t v, int tid,
                                                volatile uint32_t* rbuf) {
#pragma unroll
    for (int o = 32; o > 0; o >>= 1) {
        uint32_t w = __shfl_down(v, o, 64);
        v = (w > v) ? w : v;
    }
    __syncthreads();
    if ((tid & 63) == 0) rbuf[tid >> 6] = v;
    __syncthreads();
    uint32_t r = 0;
#pragma unroll
    for (int w = 0; w < 8; ++w) r = rbuf[w] > r ? rbuf[w] : r;
    return r;
}

__global__ __launch_bounds__(512)
void topk_loss(const bf16_t* __restrict__ S, const int* __restrict__ targets,
               const int* __restrict__ plabel, const int* __restrict__ ptable,
               float* __restrict__ out) {
    const int b    = blockIdx.x;
    const int tid  = threadIdx.x;
    const int lane = tid & 63;
    const int wave = tid >> 6;

    __shared__ int      sh_pos[4];
    __shared__ float    sh_pv[4];
    __shared__ int      sh_d;
    __shared__ int      rbuf_i[8];
    __shared__ float    rbuf_f[8];
    __shared__ uint32_t rbuf_u[8];
    __shared__ uint32_t cand_ls[64];
    __shared__ int      candcnt;
    __shared__ float    sh_numbg;

    const bf16_t* row = S + (size_t)b * N_PROXY;

    if (tid == 0) {
        int t  = targets[b];
        int py = plabel[t];
        int pos[4]; int d = 0;
        for (int j = 0; j < 4; ++j) {
            int p = ptable[py * 4 + j];
            bool dup = false;
            for (int i = 0; i < d; ++i) dup = dup || (pos[i] == p);
            if (!dup) pos[d++] = p;
        }
        sh_d = d;
        for (int j = 0; j < 4; ++j) sh_pos[j] = (j < d) ? pos[j] : -1;
        for (int j = 0; j < 4; ++j) sh_pv[j]  = (j < d) ? (float)row[pos[j]] : 0.0f;
        candcnt = 0;
    }
    __syncthreads();

    const int d  = sh_d;
    const int p0 = sh_pos[0], p1 = sh_pos[1], p2 = sh_pos[2], p3 = sh_pos[3];
    float pv[4];
#pragma unroll
    for (int j = 0; j < 4; ++j) pv[j] = sh_pv[j];

    // ---- 32 bf16 logits/thread as 16-bit sortable keys; positives -> 0 ----
    uint32_t keys[32];
#pragma unroll
    for (int j = 0; j < 4; ++j) {
        int g8 = j * 512 + tid;                     // 8-element granule
        ushort v[8];
        *(uint4*)v = *(const uint4*)(row + (size_t)g8 * 8);
#pragma unroll
        for (int q = 0; q < 8; ++q) {
            int idx = g8 * 8 + q;
            bool isp = (idx == p0) | (idx == p1) | (idx == p2) | (idx == p3);
            uint32_t bits = v[q];
            uint32_t key  = (bits & 0x8000u) ? ((~bits) & 0xFFFFu)
                                             : (bits | 0x8000u);
            keys[j * 8 + q] = isp ? 0u : key;
        }
    }

    const int need = K_SEL - d;              // backgrounds in the top-54 set

    // ---- 16-bit radix select with early exit ----
    uint32_t T = 0;
    for (int bit = 15; bit >= 0; --bit) {
        uint32_t cnd = T | (1u << bit);
        int c = 0;
#pragma unroll
        for (int j = 0; j < 32; ++j) c += (keys[j] >= cnd) ? 1 : 0;
        int ct = block_sum_i(c, tid, rbuf_i);
        if (ct >= need) {
            T = cnd;
            if (ct == need) break;           // selected set is exactly top-need
        }
    }
    const float vT = key16_to_float(T);

    // ---- stability max over backgrounds + positives ----
    uint32_t kmax = 0;
#pragma unroll
    for (int j = 0; j < 32; ++j) kmax = keys[j] > kmax ? keys[j] : kmax;
    kmax = block_max_u(kmax, tid, rbuf_u);
    float mx = key16_to_float(kmax);
    for (int j = 0; j < 4; ++j) if (j < d && pv[j] > mx) mx = pv[j];

    // ---- lse over selected set: strict-greater + exact tie fill + pos ----
    int c1 = 0; float se = 0.0f;
#pragma unroll
    for (int j = 0; j < 32; ++j) {
        if (keys[j] > T) { c1 += 1; se += __expf(key16_to_float(keys[j]) - mx); }
    }
    int   c1t = block_sum_i(c1, tid, rbuf_i);
    float set = block_sum_f(se, tid, rbuf_f);
    set += (float)(need - c1t) * __expf(vT - mx);
    for (int j = 0; j < 4; ++j) if (j < d) set += __expf(pv[j] - mx);
    const float lse = mx + logf(set);

    // ---- numerator: distinct positives + top (P-d) background values ----
    float num = 0.0f;
    for (int j = 0; j < 4; ++j) if (j < d) num += pv[j];
    if (d < P_POS) {
#pragma unroll
        for (int j = 0; j < 32; ++j) {
            if (keys[j] > T) {
                int p = atomicAdd(&candcnt, 1);
                cand_ls[p] = keys[j];
            }
        }
        __syncthreads();
        if (wave == 0) {
            const int cc = candcnt;
            uint32_t v = (lane < cc) ? cand_ls[lane] : T;   // pad with T (exact)
            float s = 0.0f;
            const int need2 = P_POS - d;                    // 1..3
            for (int it = 0; it < need2; ++it) {
                uint32_t m = v;
#pragma unroll
                for (int o = 32; o > 0; o >>= 1) {
                    uint32_t w = __shfl_xor(m, o, 64);
                    m = (w > m) ? w : m;
                }
                s += key16_to_float(m);
                unsigned long long msk = __ballot(v == m);
                int first = __ffsll(msk) - 1;
                if (lane == first) v = 0u;
            }
            if (lane == 0) sh_numbg = s;
        }
        __syncthreads();
        num += sh_numbg;
    }

    const float loss_b = lse - num * (1.0f / P_POS);
    if (tid == 0) atomicAdd(out, loss_b * (1.0f / B_SZ));
}

// ---------------------------------------------------------------------------
extern "C" void kernel_launch(void* const* d_in, const int* in_sizes, int n_in,
                              void* d_out, int out_size, void* d_ws, size_t ws_size,
                              hipStream_t stream) {
    const float* F       = (const float*)d_in[0];   // features [256,2048]
    const float* E       = (const float*)d_in[1];   // global_memory [16384,2048]
    const int*   targets = (const int*)d_in[2];     // [256]
    const int*   plabel  = (const int*)d_in[3];     // [32768]
    const int*   ptable  = (const int*)d_in[4];     // [4096,4]

    bf16_t* Fb = (bf16_t*)d_ws;                                     // 1 MB, frag-major
    bf16_t* Sb = (bf16_t*)((char*)d_ws + (size_t)B_SZ * D_DIM * 2); // 8 MB
    float*  out = (float*)d_out;

    hipMemsetAsync(d_out, 0, sizeof(float), stream);

    hipLaunchKernelGGL(conv_feat, dim3(256), dim3(256), 0, stream, F, Fb);
    hipLaunchKernelGGL(gemm_score, dim3(N_PROXY / 64), dim3(256), 0, stream,
                       Fb, E, Sb);
    hipLaunchKernelGGL(topk_loss, dim3(B_SZ), dim3(512), 0, stream,
                       Sb, targets, plabel, ptable, out);
}